// Round 3
// baseline (77.981 us; speedup 1.0000x reference)
//
#include <hip/hip_runtime.h>
#include <math.h>

#define BLK 256
#define CH 3
#define INF 3072
#define PH 34
#define PW 36    // row stride 144 B: 16B-aligned rows; w0%4==0 keeps b128 alignment
#define IMGS 4   // images per block; grid = 4096/4 = 1024 = 4 blocks/CU exactly

__device__ __forceinline__ float pointwise(float4 v, float tm, float ts, float tsm,
                                           float inv2w) {
    const float el = (v.x > 0.f) ? v.x : expm1f(v.x);      // elu
    const float lr = (v.z >= 0.f) ? v.z : 0.01f * v.z;     // leaky relu
    float r = el * tm;
    r = fmaf(-v.y, ts, r);
    r = fmaf(lr, tsm, r);
    return (v.w > 0.f) ? r - inv2w : r;                    // heaviside spike
}

__global__ __launch_bounds__(BLK) void fused_point_conv_kernel(
    const float4* __restrict__ x,       // [B, 3072] float4 (x1,x2,x3,reset)
    const float* __restrict__ tau_m1,   // [3072]
    const float* __restrict__ tau_s1,
    const float* __restrict__ tau_sm1,
    const float* __restrict__ gk,       // [3,3,3,3] OIHW (81)
    const float* __restrict__ gb,       // [3]
    const int*  __restrict__ weight,    // scalar
    float4* __restrict__ out)           // [B, 768] float4
{
    __shared__ __align__(16) float y[2][CH][PH][PW];   // double-buffered tiles
    __shared__ float sk[81];
    __shared__ float sb[CH];

    const int t = threadIdx.x;
    const int b0 = blockIdx.x * IMGS;

    // Zero ONLY the padding borders of both buffers (interior fully overwritten):
    // per channel: row0 (36) + row33 (36) + rows1..32 cols{0,33,34,35} (128) = 200
    for (int i = t; i < 2 * CH * 200; i += BLK) {
        const int buf = i / 600;
        const int rem = i - buf * 600;
        const int c = rem / 200;
        const int r = rem - c * 200;
        int row, col;
        if (r < 36)      { row = 0;  col = r; }
        else if (r < 72) { row = 33; col = r - 36; }
        else { const int rr = r - 72; row = 1 + (rr >> 2);
               const int sel = rr & 3; col = (sel == 0) ? 0 : 32 + sel; }
        y[buf][c][row][col] = 0.f;
    }
    if (t < 81) sk[t] = gk[t];
    if (t < CH) sb[t] = gb[t];

    const float inv2w = exp2f(-(float)weight[0]);
    const int h  = t >> 3;          // 0..31
    const int w0 = (t & 7) << 2;    // 0,4,...,28

    // prologue: dense coalesced load of image 0 (1 KB contiguous per wave instr)
    float4 vx[12];
    {
        const size_t base = (size_t)b0 * INF + t;
        #pragma unroll
        for (int i = 0; i < 12; ++i) vx[i] = x[base + (i << 8)];
    }

    for (int k = 0; k < IMGS; ++k) {
        const int b = b0 + k;

        // pointwise: vx -> LDS buf[k&1] (interior only)
        float* ybuf = &y[k & 1][0][0][0];
        #pragma unroll
        for (int i = 0; i < 12; ++i) {
            const int f = (i << 8) + t;
            const float tm  = tau_m1[f];
            const float ts  = tau_s1[f];
            const float tsm = tau_sm1[f];
            const int c = f >> 10, hw = f & 1023;
            const int hh = hw >> 5, ww = hw & 31;
            ybuf[(c * PH + hh + 1) * PW + ww + 1] =
                pointwise(vx[i], tm, ts, tsm, inv2w);
        }

        // prefetch next image while conv runs (lands during conv)
        if (k + 1 < IMGS) {
            const size_t base = (size_t)(b + 1) * INF + t;
            #pragma unroll
            for (int i = 0; i < 12; ++i) vx[i] = x[base + (i << 8)];
        }

        __syncthreads();   // buf[k&1] (+ borders/sk on first iter) visible

        // conv 3x3 SAME from buf[k&1]: 4 outputs/thread/channel via 6-float strips
        const float (*yc)[PH][PW] = y[k & 1];
        #pragma unroll
        for (int j = 0; j < CH; ++j) {
            const float bias = sb[j];
            float a0 = bias, a1 = bias, a2 = bias, a3 = bias;
            #pragma unroll
            for (int ci = 0; ci < CH; ++ci) {
                #pragma unroll
                for (int kh = 0; kh < 3; ++kh) {
                    const float4 s4 = *(const float4*)&yc[ci][h + kh][w0];     // b128
                    const float2 s2 = *(const float2*)&yc[ci][h + kh][w0 + 4]; // b64
                    const int kb = ((j * CH + ci) * 3 + kh) * 3;
                    const float k0 = sk[kb + 0], k1 = sk[kb + 1], k2 = sk[kb + 2];
                    a0 = fmaf(s4.x, k0, a0); a0 = fmaf(s4.y, k1, a0); a0 = fmaf(s4.z, k2, a0);
                    a1 = fmaf(s4.y, k0, a1); a1 = fmaf(s4.z, k1, a1); a1 = fmaf(s4.w, k2, a1);
                    a2 = fmaf(s4.z, k0, a2); a2 = fmaf(s4.w, k1, a2); a2 = fmaf(s2.x, k2, a2);
                    a3 = fmaf(s4.w, k0, a3); a3 = fmaf(s2.x, k1, a3); a3 = fmaf(s2.y, k2, a3);
                }
            }
            a0 = fminf(fmaxf(a0, -0.7f), 0.7f);
            a1 = fminf(fmaxf(a1, -0.7f), 0.7f);
            a2 = fminf(fmaxf(a2, -0.7f), 0.7f);
            a3 = fminf(fmaxf(a3, -0.7f), 0.7f);
            out[(size_t)b * (INF / 4) + (j << 8) + t] = make_float4(a0, a1, a2, a3);
        }
        // no trailing barrier needed: next iter writes buf[(k+1)&1], whose
        // previous readers (conv k-1) finished before THIS iter's barrier.
    }
}

extern "C" void kernel_launch(void* const* d_in, const int* in_sizes, int n_in,
                              void* d_out, int out_size, void* d_ws, size_t ws_size,
                              hipStream_t stream) {
    const float4* x      = (const float4*)d_in[0];
    const float* tau_m1  = (const float*)d_in[1];
    const float* tau_s1  = (const float*)d_in[2];
    const float* tau_sm1 = (const float*)d_in[3];
    const float* gk      = (const float*)d_in[4];
    const float* gb      = (const float*)d_in[5];
    const int*   wgt     = (const int*)d_in[6];
    float4* out = (float4*)d_out;

    const int B = in_sizes[0] / (INF * 4);   // 4096
    fused_point_conv_kernel<<<B / IMGS, BLK, 0, stream>>>(
        x, tau_m1, tau_s1, tau_sm1, gk, gb, wgt, out);
}

// Round 5
// 41.266 us; speedup vs baseline: 1.8897x; 1.8897x over previous
//
#include <hip/hip_runtime.h>
#include <math.h>

#define BLK 256
#define CH 3
#define INF 3072
#define PH 34
#define PW 36   // row stride 144 B: 16B-aligned rows; w0%4==0 keeps b128 alignment

typedef float fx4 __attribute__((ext_vector_type(4)));   // NT-store-compatible

__device__ __forceinline__ float pointwise(float4 v, float tm, float ts, float tsm,
                                           float inv2w) {
    const float el = (v.x > 0.f) ? v.x : expm1f(v.x);      // elu
    const float lr = (v.z >= 0.f) ? v.z : 0.01f * v.z;     // leaky relu
    float r = el * tm;
    r = fmaf(-v.y, ts, r);
    r = fmaf(lr, tsm, r);
    return (v.w > 0.f) ? r - inv2w : r;                    // heaviside spike
}

__global__ __launch_bounds__(BLK) void fused_point_conv_kernel(
    const float4* __restrict__ x,     // [B, 3072] float4 (x1,x2,x3,reset)
    const float4* __restrict__ tm4,   // tau_m1  as [768] float4
    const float4* __restrict__ ts4,   // tau_s1
    const float4* __restrict__ tsm4,  // tau_sm1
    const float* __restrict__ gk,     // [3,3,3,3] OIHW (81)
    const float* __restrict__ gb,     // [3]
    const int*  __restrict__ weight,  // scalar
    float* __restrict__ out)          // [B, 3072]
{
    __shared__ __align__(16) float y[CH][PH][PW];
    __shared__ float sk[81];
    __shared__ float sb[CH];

    const int b = blockIdx.x;
    const int t = threadIdx.x;

    // Zero ONLY the padding border (interior fully overwritten by phase 1):
    // per channel: row0 (36) + row33 (36) + rows1..32 cols{0,33,34,35} (128) = 200
    for (int i = t; i < CH * 200; i += BLK) {
        const int c = i / 200;
        const int r = i - c * 200;
        int row, col;
        if (r < 36)      { row = 0;  col = r; }
        else if (r < 72) { row = 33; col = r - 36; }
        else { const int rr = r - 72; row = 1 + (rr >> 2);
               const int sel = rr & 3; col = (sel == 0) ? 0 : 32 + sel; }
        y[c][row][col] = 0.f;
    }
    if (t < 81) sk[t] = gk[t];
    if (t < CH) sb[t] = gb[t];

    const float inv2w = exp2f(-(float)weight[0]);
    const int h  = t >> 3;          // 0..31
    const int w0 = (t & 7) << 2;    // 0,4,...,28
    const size_t xbase = (size_t)b * INF;

    // phase 1: pointwise, quad of consecutive features per thread per channel.
    // Disjoint from border cells -> no barrier needed before these writes.
    #pragma unroll
    for (int j = 0; j < 3; ++j) {
        const int f0 = (j << 10) + (t << 2);
        const float4 v0 = x[xbase + f0 + 0];
        const float4 v1 = x[xbase + f0 + 1];
        const float4 v2 = x[xbase + f0 + 2];
        const float4 v3 = x[xbase + f0 + 3];
        const int q = (j << 8) + t;
        const float4 tm = tm4[q], ts = ts4[q], tsm = tsm4[q];
        float* yrow = &y[j][h + 1][w0 + 1];
        yrow[0] = pointwise(v0, tm.x, ts.x, tsm.x, inv2w);
        yrow[1] = pointwise(v1, tm.y, ts.y, tsm.y, inv2w);
        yrow[2] = pointwise(v2, tm.z, ts.z, tsm.z, inv2w);
        yrow[3] = pointwise(v3, tm.w, ts.w, tsm.w, inv2w);
    }
    __syncthreads();   // one barrier: borders + sk/sb + interior all visible

    // hoist the 9 (ci,kh) strips ONCE (they don't depend on output channel j)
    float st[9][6];
    #pragma unroll
    for (int ci = 0; ci < CH; ++ci) {
        #pragma unroll
        for (int kh = 0; kh < 3; ++kh) {
            const float4 s4 = *(const float4*)&y[ci][h + kh][w0];      // ds_read_b128
            const float2 s2 = *(const float2*)&y[ci][h + kh][w0 + 4];  // ds_read_b64
            float* s = st[ci * 3 + kh];
            s[0] = s4.x; s[1] = s4.y; s[2] = s4.z;
            s[3] = s4.w; s[4] = s2.x; s[5] = s2.y;
        }
    }

    // phase 2: 3x3 SAME conv entirely from registers, 4 outputs/thread/channel
    #pragma unroll
    for (int j = 0; j < CH; ++j) {
        const float bias = sb[j];
        float a0 = bias, a1 = bias, a2 = bias, a3 = bias;
        #pragma unroll
        for (int ci = 0; ci < CH; ++ci) {
            #pragma unroll
            for (int kh = 0; kh < 3; ++kh) {
                const float* s = st[ci * 3 + kh];
                const int kb = ((j * CH + ci) * 3 + kh) * 3;
                const float k0 = sk[kb + 0], k1 = sk[kb + 1], k2 = sk[kb + 2];
                a0 = fmaf(s[0], k0, a0); a0 = fmaf(s[1], k1, a0); a0 = fmaf(s[2], k2, a0);
                a1 = fmaf(s[1], k0, a1); a1 = fmaf(s[2], k1, a1); a1 = fmaf(s[3], k2, a1);
                a2 = fmaf(s[2], k0, a2); a2 = fmaf(s[3], k1, a2); a2 = fmaf(s[4], k2, a2);
                a3 = fmaf(s[3], k0, a3); a3 = fmaf(s[4], k1, a3); a3 = fmaf(s[5], k2, a3);
            }
        }
        a0 = fminf(fmaxf(a0, -0.7f), 0.7f);
        a1 = fminf(fmaxf(a1, -0.7f), 0.7f);
        a2 = fminf(fmaxf(a2, -0.7f), 0.7f);
        a3 = fminf(fmaxf(a3, -0.7f), 0.7f);
        fx4 r; r.x = a0; r.y = a1; r.z = a2; r.w = a3;
        // non-temporal: out is write-once, keep x resident in L2/L3
        __builtin_nontemporal_store(
            r, (fx4*)&out[(size_t)b * INF + ((j << 8) + t) * 4]);
    }
}

extern "C" void kernel_launch(void* const* d_in, const int* in_sizes, int n_in,
                              void* d_out, int out_size, void* d_ws, size_t ws_size,
                              hipStream_t stream) {
    const float4* x    = (const float4*)d_in[0];
    const float4* tm4  = (const float4*)d_in[1];
    const float4* ts4  = (const float4*)d_in[2];
    const float4* tsm4 = (const float4*)d_in[3];
    const float*  gk   = (const float*)d_in[4];
    const float*  gb   = (const float*)d_in[5];
    const int*    wgt  = (const int*)d_in[6];
    float* out = (float*)d_out;

    const int B = in_sizes[0] / (INF * 4);   // 4096
    fused_point_conv_kernel<<<B, BLK, 0, stream>>>(
        x, tm4, ts4, tsm4, gk, gb, wgt, out);
}